// Round 7
// baseline (2189.732 us; speedup 1.0000x reference)
//
#include <hip/hip_runtime.h>

#define B_ 16
#define S_ 4096
#define D_ 256
#define H_ 256
#define BPB 4            // batches per block
#define TPB 512          // 8 waves
#define NT 2             // 16-col N-tiles per wave (wave owns 32 cols)

typedef _Float16 h8v __attribute__((ext_vector_type(8)));
typedef float f4 __attribute__((ext_vector_type(4)));

// Kernel 1: xp[row][h] = sum_d x[row][d] * Wx[d][h] + bias[h], into d_out.
__global__ __launch_bounds__(256) void xproj_kernel(
    const float* __restrict__ x, const float* __restrict__ Wx,
    const float* __restrict__ bias, float* __restrict__ out)
{
    __shared__ float xs[32 * 256];
    const int tid = threadIdx.x;
    const long long row0 = (long long)blockIdx.x * 32;

    {
        const f4* __restrict__ xg = (const f4*)(x + row0 * D_);
        f4* xsv = (f4*)xs;
        #pragma unroll
        for (int k = 0; k < 8; ++k)
            xsv[tid + k * 256] = xg[tid + k * 256];
    }
    __syncthreads();

    const int j = tid;
    float acc[32];
    const float bj = bias[j];
    #pragma unroll
    for (int r = 0; r < 32; ++r) acc[r] = bj;

    for (int d4 = 0; d4 < D_ / 4; ++d4) {
        const float w0 = Wx[(d4 * 4 + 0) * H_ + j];
        const float w1 = Wx[(d4 * 4 + 1) * H_ + j];
        const float w2 = Wx[(d4 * 4 + 2) * H_ + j];
        const float w3 = Wx[(d4 * 4 + 3) * H_ + j];
        #pragma unroll
        for (int r = 0; r < 32; ++r) {
            f4 xv = *(const f4*)&xs[r * 256 + d4 * 4];
            acc[r] = fmaf(xv.x, w0, acc[r]);
            acc[r] = fmaf(xv.y, w1, acc[r]);
            acc[r] = fmaf(xv.z, w2, acc[r]);
            acc[r] = fmaf(xv.w, w3, acc[r]);
        }
    }
    #pragma unroll
    for (int r = 0; r < 32; ++r)
        out[(row0 + r) * H_ + j] = acc[r];
}

// Kernel 2: MFMA-batched scan. 4 blocks x 4 batches, 512 threads (8 waves).
// Per step: H_new[b][j] = tanh(xp[b][t][j] + sum_i h[b][i] Wh[i][j]) for the
// block's 4 batches via 16x16x32 f16 MFMA (M rows = batches, N = j).
// Wh resident in registers as B-frags; h in double-buffered LDS [4][264] f16.
// C redistributed through wave-private c_lds (intra-wave, no barrier), each
// thread finishes 2 outputs. ONE barrier per step.
__global__ __launch_bounds__(TPB, 2) void scan_kernel(
    const float* __restrict__ Wh, const float* __restrict__ state0,
    float* __restrict__ out)
{
    __shared__ __align__(16) _Float16 h_lds[2][4 * 264];  // rows 0-3, stride 264
    __shared__ float c_lds[4][256];                       // wave-private col ranges

    const int tid = threadIdx.x;
    const int l   = tid & 63;
    const int wav = tid >> 6;        // 0..7, owns cols [32*wav, 32*wav+32)
    const int lc  = l & 15;
    const int kg  = l >> 4;          // 0..3 (k-group)
    const int blk = blockIdx.x;      // 0..3

    // B-fragments: Wh[k][j] f32 -> f16. frag[nt][ks]: lane holds col 32wav+16nt+lc,
    // k = 32*ks + 8*kg + e  (same k-mapping used for A => permutation-safe).
    h8v bf[NT][8];
    #pragma unroll
    for (int nt = 0; nt < NT; ++nt) {
        #pragma unroll
        for (int ks = 0; ks < 8; ++ks) {
            #pragma unroll
            for (int e = 0; e < 8; ++e) {
                const int k = 32 * ks + 8 * kg + e;
                const int j = 32 * wav + 16 * nt + lc;
                bf[nt][ks][e] = (_Float16)Wh[k * H_ + j];
            }
        }
    }

    // init h buffer 0 (rows = the block's 4 batches)
    for (int idx = tid; idx < 4 * H_; idx += TPB) {
        const int r = idx >> 8, j = idx & 255;
        h_lds[0][r * 264 + j] = (_Float16)state0[(BPB * blk + r) * H_ + j];
    }

    // epilogue ownership: thread -> col, row pair {r0, r0+1}
    const int col = 32 * wav + (l & 31);
    const int r0  = (l >> 5) * 2;
    float* __restrict__ ob0 = out + (long long)(BPB * blk + r0)     * S_ * H_;
    float* __restrict__ ob1 = out + (long long)(BPB * blk + r0 + 1) * S_ * H_;

    // xp ring, distance 2: xa* for even steps, xb* for odd steps
    float xa0 = ob0[0 * H_ + col], xa1 = ob1[0 * H_ + col];
    float xb0 = ob0[1 * H_ + col], xb1 = ob1[1 * H_ + col];
    __syncthreads();

    const int arow = (lc & 3) * 264 + 8 * kg;  // rows duplicated: no divergence

#define STEP(CUR, T, X0, X1)                                                   \
    {                                                                          \
        const _Float16* hb = h_lds[CUR];                                       \
        f4 acc0 = {0.f, 0.f, 0.f, 0.f};                                        \
        f4 acc1 = {0.f, 0.f, 0.f, 0.f};                                        \
        _Pragma("unroll")                                                      \
        for (int ks = 0; ks < 8; ++ks) {                                       \
            h8v af = *(const h8v*)&hb[arow + 32 * ks];                         \
            acc0 = __builtin_amdgcn_mfma_f32_16x16x32_f16(af, bf[0][ks],       \
                                                          acc0, 0, 0, 0);      \
            acc1 = __builtin_amdgcn_mfma_f32_16x16x32_f16(af, bf[1][ks],       \
                                                          acc1, 0, 0, 0);      \
        }                                                                      \
        if (kg == 0) { /* valid C rows 0-3 live in lanes 0-15 */               \
            _Pragma("unroll")                                                  \
            for (int r = 0; r < 4; ++r) {                                      \
                c_lds[r][32 * wav + lc]      = acc0[r];                        \
                c_lds[r][32 * wav + 16 + lc] = acc1[r];                        \
            }                                                                  \
        }                                                                      \
        /* intra-wave exchange (wave-private cols): compiler orders via lgkm */\
        const float pre0 = c_lds[r0][col]     + X0;                            \
        const float pre1 = c_lds[r0 + 1][col] + X1;                            \
        const float e0 = __builtin_amdgcn_exp2f(pre0 * 2.8853900817779268f);   \
        const float e1 = __builtin_amdgcn_exp2f(pre1 * 2.8853900817779268f);   \
        const float hn0 = fmaf(-2.f, __builtin_amdgcn_rcpf(e0 + 1.f), 1.f);    \
        const float hn1 = fmaf(-2.f, __builtin_amdgcn_rcpf(e1 + 1.f), 1.f);    \
        ob0[(long long)(T) * H_ + col] = hn0;                                  \
        ob1[(long long)(T) * H_ + col] = hn1;                                  \
        _Float16* hw = h_lds[(CUR) ^ 1];                                       \
        hw[r0 * 264 + col]       = (_Float16)hn0;                              \
        hw[(r0 + 1) * 264 + col] = (_Float16)hn1;                              \
        const int tn = (T) + 2;                                                \
        if (tn < S_) {                                                         \
            X0 = ob0[(long long)tn * H_ + col];                                \
            X1 = ob1[(long long)tn * H_ + col];                                \
        }                                                                      \
        __syncthreads();                                                       \
    }

    for (int t2 = 0; t2 < S_; t2 += 2) {
        STEP(0, t2,     xa0, xa1)
        STEP(1, t2 + 1, xb0, xb1)
    }
#undef STEP
}

extern "C" void kernel_launch(void* const* d_in, const int* in_sizes, int n_in,
                              void* d_out, int out_size, void* d_ws, size_t ws_size,
                              hipStream_t stream) {
    const float* x  = (const float*)d_in[0];   // [B,S,D]
    const float* s0 = (const float*)d_in[1];   // [B,H]
    const float* Wx = (const float*)d_in[2];   // [D,H]
    const float* Wh = (const float*)d_in[3];   // [H,H]
    const float* bv = (const float*)d_in[4];   // [H]
    float* out = (float*)d_out;                // [B,S,H]

    xproj_kernel<<<dim3((B_ * S_) / 32), dim3(256), 0, stream>>>(x, Wx, bv, out);
    scan_kernel<<<dim3(B_ / BPB), dim3(TPB), 0, stream>>>(Wh, s0, out);
}

// Round 8
// 1865.117 us; speedup vs baseline: 1.1740x; 1.1740x over previous
//
#include <hip/hip_runtime.h>

#define B_ 16
#define S_ 4096
#define D_ 256
#define H_ 256

typedef _Float16 h2 __attribute__((ext_vector_type(2)));
typedef _Float16 h8 __attribute__((ext_vector_type(8)));
typedef float f4 __attribute__((ext_vector_type(4)));

static __device__ __forceinline__ float fdot2f(h2 a, h2 b, float c) {
    return __builtin_amdgcn_fdot2(a, b, c, false);
}

// pure-VALU cross-lane via DPP quad_perm; ctrl must be ICE
template <int CTRL>
static __device__ __forceinline__ float dpp_qp(float v) {
    int r = __builtin_amdgcn_update_dpp(0, __float_as_int(v), CTRL, 0xF, 0xF, true);
    return __int_as_float(r);
}
#define DPP_XOR1 0xB1   // quad_perm [1,0,3,2]
#define DPP_XOR2 0x4E   // quad_perm [2,3,0,1]

// LDS-only barrier: drain LDS ops, NOT vmcnt — global stores/loads stay in
// flight across the barrier (T4: never vmcnt(0) in the main loop).
static __device__ __forceinline__ void lds_barrier() {
    asm volatile("s_waitcnt lgkmcnt(0)" ::: "memory");
    __builtin_amdgcn_s_barrier();
}

// swizzled f16-index for h element i in a 256-entry LDS buffer:
// slice s=i>>6 (128B block), chunk r=(i>>3)&7 (16B), XOR-placed so the 4
// distinct addresses of a quad's distributed read hit disjoint bank quads.
static __device__ __forceinline__ int swz(int i) {
    const int s = i >> 6, r = (i >> 3) & 7, e = i & 7;
    return 64 * s + 8 * ((r + 2 * s) & 7) + e;
}

// Kernel 1: xp[row][h] = sum_d x[row][d] * Wx[d][h] + bias[h], into d_out.
__global__ __launch_bounds__(256) void xproj_kernel(
    const float* __restrict__ x, const float* __restrict__ Wx,
    const float* __restrict__ bias, float* __restrict__ out)
{
    __shared__ float xs[32 * 256];
    const int tid = threadIdx.x;
    const long long row0 = (long long)blockIdx.x * 32;

    {
        const f4* __restrict__ xg = (const f4*)(x + row0 * D_);
        f4* xsv = (f4*)xs;
        #pragma unroll
        for (int k = 0; k < 8; ++k)
            xsv[tid + k * 256] = xg[tid + k * 256];
    }
    __syncthreads();

    const int j = tid;
    float acc[32];
    const float bj = bias[j];
    #pragma unroll
    for (int r = 0; r < 32; ++r) acc[r] = bj;

    for (int d4 = 0; d4 < D_ / 4; ++d4) {
        const float w0 = Wx[(d4 * 4 + 0) * H_ + j];
        const float w1 = Wx[(d4 * 4 + 1) * H_ + j];
        const float w2 = Wx[(d4 * 4 + 2) * H_ + j];
        const float w3 = Wx[(d4 * 4 + 3) * H_ + j];
        #pragma unroll
        for (int r = 0; r < 32; ++r) {
            f4 xv = *(const f4*)&xs[r * 256 + d4 * 4];
            acc[r] = fmaf(xv.x, w0, acc[r]);
            acc[r] = fmaf(xv.y, w1, acc[r]);
            acc[r] = fmaf(xv.z, w2, acc[r]);
            acc[r] = fmaf(xv.w, w3, acc[r]);
        }
    }
    #pragma unroll
    for (int r = 0; r < 32; ++r)
        out[(row0 + r) * H_ + j] = acc[r];
}

// Kernel 2: sequential scan, one block (CU) per batch, 256 threads.
// Identical to round-4 structure (best so far: 987 cy/step) EXCEPT the
// per-step barrier drains lgkmcnt only — the hn global store and xp
// prefetch load no longer serialize into every step via vmcnt(0).
__global__ __launch_bounds__(256, 1) void scan_kernel(
    const float* __restrict__ Wh, const float* __restrict__ state0,
    float* __restrict__ out)
{
    __shared__ __align__(16) _Float16 hbuf[2][H_];
    const int tid = threadIdx.x;
    const int s = tid & 3;          // i-slice
    const int q = tid >> 2;         // j-group
    const int b = blockIdx.x;
    const bool o1 = (s & 1) != 0;
    const bool o2 = (s & 2) != 0;

    // W[i][j] for i in [64s,64s+64), j in [4q,4q+4), packed as h2 i-pairs.
    h2 w[4][32];
    #pragma unroll
    for (int jj = 0; jj < 4; ++jj) {
        const int j = 4 * q + jj;
        #pragma unroll
        for (int ii = 0; ii < 32; ++ii) {
            const int i = 64 * s + 2 * ii;
            h2 p;
            p[0] = (_Float16)Wh[(long long)i * H_ + j];
            p[1] = (_Float16)Wh[(long long)(i + 1) * H_ + j];
            w[jj][ii] = p;
        }
    }

    hbuf[0][swz(tid)] = (_Float16)state0[b * H_ + tid];

    float* __restrict__ outb = out + (long long)b * S_ * H_;

    // xp prefetch ring, distance 4 (static indices via unroll-4)
    float xr[4];
    #pragma unroll
    for (int k = 0; k < 4; ++k)
        xr[k] = outb[(long long)k * H_ + tid];
    __syncthreads();   // once, before the loop: full drain is fine here

    // chunk r holds h[64s+8r .. +8] at f16-pos 64s + 8*((r+2s)&7)
    #pragma unroll 4
    for (int st = 0; st < S_; ++st) {
        const int p = st & 1;
        const _Float16* hb = hbuf[p];

        h8 hv[8];
        #pragma unroll
        for (int r = 0; r < 8; ++r)
            hv[r] = *(const h8*)&hb[64 * s + 8 * ((r + 2 * s) & 7)];

        float acc0 = 0.f, acc1 = 0.f, acc2 = 0.f, acc3 = 0.f;
        #pragma unroll
        for (int r = 0; r < 8; ++r) {
            union { h8 v; h2 pr[4]; } u;
            u.v = hv[r];
            #pragma unroll
            for (int m = 0; m < 4; ++m) {
                const int ii = 4 * r + m;
                acc0 = fdot2f(u.pr[m], w[0][ii], acc0);
                acc1 = fdot2f(u.pr[m], w[1][ii], acc1);
                acc2 = fdot2f(u.pr[m], w[2][ii], acc2);
                acc3 = fdot2f(u.pr[m], w[3][ii], acc3);
            }
        }

        // reduce-scatter across the 4 slice-threads (pure VALU DPP)
        float vA = o1 ? acc1 : acc0;
        float vB = o1 ? acc3 : acc2;
        float sA = o1 ? acc0 : acc1;
        float sB = o1 ? acc2 : acc3;
        vA += dpp_qp<DPP_XOR1>(sA);
        vB += dpp_qp<DPP_XOR1>(sB);
        float v   = o2 ? vB : vA;
        float snd = o2 ? vA : vB;
        v += dpp_qp<DPP_XOR2>(snd);
        // v = full dot for j = 4q + s = tid

        const float pre = v + xr[st & 3];
        const float e = __builtin_amdgcn_exp2f(pre * 2.8853900817779268f);
        const float hn = fmaf(-2.f, __builtin_amdgcn_rcpf(e + 1.f), 1.f);

        outb[(long long)st * H_ + tid] = hn;       // stays in flight
        hbuf[p ^ 1][swz(tid)] = (_Float16)hn;      // publish h for t+1

        const int nt = st + 4;
        xr[st & 3] = (nt < S_) ? outb[(long long)nt * H_ + tid] : 0.f;
        lds_barrier();   // lgkmcnt(0) + s_barrier — NO vmcnt drain
    }
}

extern "C" void kernel_launch(void* const* d_in, const int* in_sizes, int n_in,
                              void* d_out, int out_size, void* d_ws, size_t ws_size,
                              hipStream_t stream) {
    const float* x  = (const float*)d_in[0];   // [B,S,D]
    const float* s0 = (const float*)d_in[1];   // [B,H]
    const float* Wx = (const float*)d_in[2];   // [D,H]
    const float* Wh = (const float*)d_in[3];   // [H,H]
    const float* bv = (const float*)d_in[4];   // [H]
    float* out = (float*)d_out;                // [B,S,H]

    xproj_kernel<<<dim3((B_ * S_) / 32), dim3(256), 0, stream>>>(x, Wx, bv, out);
    scan_kernel<<<dim3(B_), dim3(256), 0, stream>>>(Wh, s0, out);
}